// Round 14
// baseline (238.581 us; speedup 1.0000x reference)
//
#include <hip/hip_runtime.h>

#define N_NODES 50000
#define N_EDGES 800000
#define NGRAPH  128
#define XPITCH  72   // ushort pitch: 72*2=144B, 16B-aligned rows, 2-way (free) banks
#define NB      391  // dst buckets of 128 nodes
#define SEPB    8192
#define SBLKS   ((N_EDGES + SEPB - 1) / SEPB)
#define NGRP    3125 // 16-node groups (50000/16 exact)
#define KSPLIT  1152 // kA groups in the scatter dispatch (cover ~12us of scatter)
#define STRIDE  64   // per-node srcList slots (max Poisson(16) deg << 64)
#define SENT    N_NODES  // sentinel src -> v row N_NODES = -inf => relu contribution 0
#define BKT     2560 // fixed packs region per bucket (mean 2048, +11 sigma)
#define PBLK    ((WT_TOTAL + 255) / 256)  // kPrep elementwise blocks; +5 fold appended

typedef short bf16x8 __attribute__((ext_vector_type(8)));
typedef float f32x4  __attribute__((ext_vector_type(4)));

// ---------------------------------------------------------------------------
// helpers
// ---------------------------------------------------------------------------

__device__ __forceinline__ float atomAddF(float* p, float v) {
#if defined(__gfx950__) || defined(__AMDGCN__)
    return unsafeAtomicAdd(p, v);
#else
    return atomicAdd(p, v);
#endif
}

__device__ __forceinline__ unsigned short f2bf(float x) {  // RNE f32 -> bf16
    unsigned u = __builtin_bit_cast(unsigned, x);
    u += 0x7fffu + ((u >> 16) & 1u);
    return (unsigned short)(u >> 16);
}
__device__ __forceinline__ float bf2f(unsigned short h) {
    return __builtin_bit_cast(float, (unsigned)h << 16);
}

__device__ __forceinline__ f32x4 mk4(float b) { f32x4 a = {b, b, b, b}; return a; }

// One 16x16 tile vs weight mat, A-frags preloaded in regs.
template<int NKC, int KROW>
__device__ __forceinline__ f32x4 w_tile(const bf16x8* a,
                                        const unsigned short* __restrict__ Wm,
                                        int nt, int col, int quad, f32x4 acc) {
    const unsigned short* wp = Wm + (nt * 16 + col) * KROW + quad * 8;
#pragma unroll
    for (int c = 0; c < NKC; ++c) {
        bf16x8 b = *(const bf16x8*)(wp + c * 32);
        acc = __builtin_amdgcn_mfma_f32_16x16x32_bf16(a[c], b, acc, 0, 0, 0);
    }
    return acc;
}

// load A-frags from a 16-node slice
template<int NKC>
__device__ __forceinline__ void a_load(const unsigned short* __restrict__ sl,
                                       int col, int quad, bf16x8* a) {
    a[0] = *(const bf16x8*)(sl + col * XPITCH + quad * 8);
    if (NKC > 1) a[1] = *(const bf16x8*)(sl + col * XPITCH + quad * 8 + 32);
}

// write this wave's 16-col tile into the given slice (double-buffer target)
__device__ __forceinline__ void w_store1(unsigned short* __restrict__ sl,
                                         int wv, int col, int quad, f32x4 acc,
                                         bool relu) {
#pragma unroll
    for (int r = 0; r < 4; ++r) {
        float x = acc[r];
        if (relu) x = fmaxf(x, 0.f);
        sl[(quad * 4 + r) * XPITCH + wv * 16 + col] = f2bf(x);
    }
}

// store this wave's 16-col tile to global rows (node-major bf16[64])
__device__ __forceinline__ void g_store1(unsigned short* __restrict__ g, int gn0,
                                         int wv, int col, int quad, f32x4 acc) {
#pragma unroll
    for (int r = 0; r < 4; ++r) {
        int node = gn0 + quad * 4 + r;
        if (node < N_NODES)
            g[(size_t)node * 64 + wv * 16 + col] = f2bf(acc[r]);
    }
}

// ---------------------------------------------------------------------------
// per-wave fused aggregation over sentinel-padded fixed-stride CSR.
// (Round-6 proven form: serial over the 4 nodes, 4 gathers in flight.)
// ---------------------------------------------------------------------------
__device__ __forceinline__ void wave_agg4(const int* dg, unsigned short* __restrict__ sl,
                                          const unsigned short* __restrict__ u,
                                          const unsigned short* __restrict__ vin,
                                          const unsigned short* __restrict__ srcList,
                                          int gn0, int wv, int lane) {
    int sub = lane & 15, q = lane >> 4;
    int n0 = gn0 + wv * 4;
    ushort4 uu4[4];
#pragma unroll
    for (int mi = 0; mi < 4; ++mi)
        uu4[mi] = *(const ushort4*)(u + (size_t)(n0 + mi) * 64 + sub * 4);

#pragma unroll
    for (int mi = 0; mi < 4; ++mi) {
        int m = wv * 4 + mi;
        float u0 = bf2f(uu4[mi].x), u1 = bf2f(uu4[mi].y);
        float u2 = bf2f(uu4[mi].z), u3 = bf2f(uu4[mi].w);
        int pdeg = (dg[m] + 15) & ~15;
        size_t b = (size_t)(n0 + mi) * STRIDE;
        float a0 = 0.f, a1 = 0.f, a2 = 0.f, a3 = 0.f;

        for (int g0 = 0; g0 < pdeg; g0 += 16) {
            ushort4 ss = *(const ushort4*)(srcList + b + g0 + 4 * q);  // 8B aligned
            int s0 = ss.x, s1 = ss.y, s2 = ss.z, s3 = ss.w;
            ushort4 w0 = *(const ushort4*)(vin + (size_t)s0 * 64 + sub * 4);
            ushort4 w1 = *(const ushort4*)(vin + (size_t)s1 * 64 + sub * 4);
            ushort4 w2 = *(const ushort4*)(vin + (size_t)s2 * 64 + sub * 4);
            ushort4 w3 = *(const ushort4*)(vin + (size_t)s3 * 64 + sub * 4);
            a0 += fmaxf(u0 + bf2f(w0.x), 0.f) + fmaxf(u0 + bf2f(w1.x), 0.f)
                + fmaxf(u0 + bf2f(w2.x), 0.f) + fmaxf(u0 + bf2f(w3.x), 0.f);
            a1 += fmaxf(u1 + bf2f(w0.y), 0.f) + fmaxf(u1 + bf2f(w1.y), 0.f)
                + fmaxf(u1 + bf2f(w2.y), 0.f) + fmaxf(u1 + bf2f(w3.y), 0.f);
            a2 += fmaxf(u2 + bf2f(w0.z), 0.f) + fmaxf(u2 + bf2f(w1.z), 0.f)
                + fmaxf(u2 + bf2f(w2.z), 0.f) + fmaxf(u2 + bf2f(w3.z), 0.f);
            a3 += fmaxf(u3 + bf2f(w0.w), 0.f) + fmaxf(u3 + bf2f(w1.w), 0.f)
                + fmaxf(u3 + bf2f(w2.w), 0.f) + fmaxf(u3 + bf2f(w3.w), 0.f);
        }

        a0 += __shfl_xor(a0, 16); a0 += __shfl_xor(a0, 32);
        a1 += __shfl_xor(a1, 16); a1 += __shfl_xor(a1, 32);
        a2 += __shfl_xor(a2, 16); a2 += __shfl_xor(a2, 32);
        a3 += __shfl_xor(a3, 16); a3 += __shfl_xor(a3, 32);

        if (q == 0) {
            ushort4 o;
            o.x = f2bf(a0); o.y = f2bf(a1); o.z = f2bf(a2); o.w = f2bf(a3);
            *(ushort4*)&sl[m * XPITCH + sub * 4] = o;
        }
    }
}

// ---------------------------------------------------------------------------
// kA body (folded chain, double-buffered SL): x,pos -> u, v0. Shared by the
// two front-end dispatches (disjoint group ranges).
// ---------------------------------------------------------------------------
__device__ __forceinline__ void kA_body(
    int gn0, int tid,
    const float* __restrict__ x, const float* __restrict__ pos,
    const unsigned short* __restrict__ WT, const float* __restrict__ fb,
    const float* __restrict__ nb1, const float* __restrict__ lW1f,
    unsigned short* __restrict__ u, unsigned short* __restrict__ v,
    unsigned short (*SL)[16 * XPITCH], float* pw) {
    int lane = tid & 63;
    int wv = __builtin_amdgcn_readfirstlane(tid >> 6);
    int col = lane & 15, quad = lane >> 4;

    for (int idx = tid; idx < 512; idx += 256) {
        int m = idx >> 5, k = idx & 31;
        int node = gn0 + m;
        float val = (k < 16) ? x[(size_t)node * 16 + k] : 0.f;
        SL[0][m * XPITCH + k] = f2bf(val);
    }
    if (tid < 48) {
        int node = gn0 + tid / 3;
        pw[tid] = pos[(size_t)node * 3 + tid % 3];
    }
    __syncthreads();

    bf16x8 a[2];
    f32x4 acc;

    a_load<1>(SL[0], col, quad, a);
    acc = w_tile<1, 32>(a, WT + 0 /*OFF_NW1T*/, wv, col, quad,
                        mk4(nb1[wv * 16 + col]));
    w_store1(SL[1], wv, col, quad, acc, true);
    __syncthreads();

    const unsigned short* FA = WT + 6144 /*OFF_LYR*/;  // nW2·A0 (folded)
    const unsigned short* FB = FA + 4096;              // nW2·B0 (folded)
    const float* W1c = lW1f + 128 * 64;
    int ch = wv * 16 + col;

    a_load<2>(SL[1], col, quad, a);
    acc = w_tile<2, 64>(a, FA, wv, col, quad, mk4(fb[ch]));       // + bA
    g_store1(u, gn0, wv, col, quad, acc);

    acc = w_tile<2, 64>(a, FB, wv, col, quad, mk4(fb[64 + ch]));  // + bB (incl lb1)
    float w0 = W1c[ch], w1 = W1c[64 + ch], w2 = W1c[128 + ch];
#pragma unroll
    for (int r = 0; r < 4; ++r) {
        int rr = quad * 4 + r;
        acc[r] += pw[rr * 3 + 0] * w0 + pw[rr * 3 + 1] * w1 + pw[rr * 3 + 2] * w2;
    }
    g_store1(v, gn0, wv, col, quad, acc);
}

// ---------------------------------------------------------------------------
// kPrep: blocks [0,PBLK): elementwise transpose+bf16 (skips fold-owned/dead
// slots); zeroes out; inits cursor[b]=b*BKT (fixed bucket regions); writes
// -inf sentinel rows. Blocks [PBLK,PBLK+5): f32 weight folding (R10 form).
// ---------------------------------------------------------------------------
#define OFF_NW1T  0
#define OFF_NW2T  2048
#define OFF_LYR   6144
#define LYR_SZ    20480
#define OFF_LIN1T 67584
#define OFF_LIN2T 69632
#define WT_TOTAL  70144

__global__ __launch_bounds__(256) void kPrep(
    const float* __restrict__ nW1, const float* __restrict__ nW2,
    const float* __restrict__ lW1, const float* __restrict__ lW2,
    const float* __restrict__ gW1, const float* __restrict__ gW2,
    const float* __restrict__ lin1W, const float* __restrict__ lin2W,
    const float* __restrict__ nb2, const float* __restrict__ lb1,
    const float* __restrict__ lb2,
    unsigned short* __restrict__ WT, float* __restrict__ fb,
    int* __restrict__ cursor, float* __restrict__ out,
    unsigned short* __restrict__ v0, unsigned short* __restrict__ v1) {
    int tid = threadIdx.x;

    if (blockIdx.x >= PBLK) {
        // ---- fold blocks (R10 fast form) ----
        __shared__ float foldP[64 * 65];
        int f = blockIdx.x - PBLK;
        const float* Wl;
        const float* Wr;
        size_t slot;
        if (f == 0)      { Wl = nW2;          Wr = lW1;            slot = OFF_LYR; }
        else if (f == 1) { Wl = nW2;          Wr = lW1 + 64 * 64;  slot = OFF_LYR + 4096; }
        else { int l = f - 2;
               Wl = lW2 + (size_t)l * 4096;   Wr = gW1 + (size_t)l * 4096;
               slot = OFF_LYR + (size_t)l * LYR_SZ + 2 * 4096; }

        int n = tid & 63;   // lane -> output col (coalesced Wr reads)
        int w = tid >> 6;   // wave -> 16 consecutive kk rows
        float acc[16];
#pragma unroll
        for (int i2 = 0; i2 < 16; ++i2) acc[i2] = 0.f;
        for (int t0 = 0; t0 < 64; t0 += 16) {
            float wr[16];
#pragma unroll
            for (int tt = 0; tt < 16; ++tt) wr[tt] = Wr[(t0 + tt) * 64 + n];
#pragma unroll
            for (int i2 = 0; i2 < 16; ++i2) {
                int kk = w * 16 + i2;
#pragma unroll
                for (int tt = 0; tt < 16; ++tt)
                    acc[i2] += Wl[kk * 64 + t0 + tt] * wr[tt];  // Wl wave-uniform
            }
        }
#pragma unroll
        for (int i2 = 0; i2 < 16; ++i2)
            foldP[(w * 16 + i2) * 65 + n] = acc[i2];
        __syncthreads();
        for (int idx = tid; idx < 4096; idx += 256) {
            int nn = idx >> 6, kk = idx & 63;
            WT[slot + idx] = f2bf(foldP[kk * 65 + nn]);   // coalesced WT write
        }
        if (tid < 64) {
            if (f == 0) {
                float s = 0.f;
                for (int t = 0; t < 64; ++t) s += nb2[t] * lW1[t * 64 + tid];
                fb[tid] = s;                     // bA
            } else if (f == 1) {
                float s = 0.f;
                for (int t = 0; t < 64; ++t) s += nb2[t] * lW1[(64 + t) * 64 + tid];
                fb[64 + tid] = s + lb1[tid];     // bB (+lb1 layer0)
            } else {
                int l = f - 2;
                float s = 0.f;
                for (int t = 0; t < 64; ++t)
                    s += lb2[l * 64 + t] * gW1[(size_t)l * 4096 + t * 64 + tid];
                fb[128 + l * 64 + tid] = s;      // lbg[l]
            }
        }
        return;
    }

    int i = blockIdx.x * 256 + tid;
    if (blockIdx.x == 0) {
        for (int k = tid; k < NB; k += 256) cursor[k] = k * BKT;
        for (int k = tid; k < NGRAPH * 8; k += 256) out[k] = 0.f;
    }
    if (i < 64) {  // sentinel row = -inf (bf16 0xFF80)
        v0[(size_t)N_NODES * 64 + i] = 0xFF80;
        v1[(size_t)N_NODES * 64 + i] = 0xFF80;
    }
    if (i >= WT_TOTAL) return;
    int j = i;
    if (j < 2048) {
        int n = j >> 5, k = j & 31;
        WT[i] = (k < 16) ? f2bf(nW1[k * 64 + n]) : 0;
        return;
    }
    j -= 2048;
    if (j < 4096) return;  // nW2T: dead (folded)
    j -= 4096;
    if (j < 3 * LYR_SZ) {
        int l = j / LYR_SZ;  j -= l * LYR_SZ;
        int m = j >> 12;     j &= 4095;
        if (m == 2 || m == 3 || (l == 0 && m < 2)) return;  // fold-owned / dead
        int n = j >> 6, k = j & 63;
        const float* src;
        if (m == 0)      src = lW1 + (size_t)l * 131 * 64;
        else if (m == 1) src = lW1 + (size_t)l * 131 * 64 + 64 * 64;
        else             src = gW2 + (size_t)l * 4096;
        WT[i] = f2bf(src[k * 64 + n]);
        return;
    }
    j -= 3 * LYR_SZ;
    if (j < 2048) {
        int n = j >> 6, k = j & 63;
        WT[i] = f2bf(lin1W[k * 32 + n]);
        return;
    }
    j -= 2048;
    {
        int n = j >> 5, k = j & 31;
        WT[i] = (n < 8) ? f2bf(lin2W[k * 8 + n]) : 0;
    }
}

// ---------------------------------------------------------------------------
// kScatA: blocks [0,SBLKS): DIRECT bucket scatter into fixed bucket regions.
// Blocks [SBLKS, SBLKS+KSPLIT): kA groups [0,KSPLIT) — sized to just cover
// the scatter (~12us); remaining kA groups run in kSortA to cover the sort.
// ---------------------------------------------------------------------------
__global__ __launch_bounds__(256) void kScatA(
    const int* __restrict__ ei, int* __restrict__ cursor,
    int* __restrict__ packs,
    const float* __restrict__ x, const float* __restrict__ pos,
    const unsigned short* __restrict__ WT, const float* __restrict__ fb,
    const float* __restrict__ nb1,
    const float* __restrict__ lW1f,
    unsigned short* __restrict__ u, unsigned short* __restrict__ v) {
    __shared__ int hist[NB];
    __shared__ int gbase[NB];
    __shared__ unsigned short SL[2][16 * XPITCH];
    __shared__ float pw[48];
    int tid = threadIdx.x;

    if (blockIdx.x < SBLKS) {
        int base = blockIdx.x * SEPB;
        for (int i = tid; i < NB; i += 256) hist[i] = 0;
        __syncthreads();

        int myPack[SEPB / 256];
        unsigned short myRank[SEPB / 256];
#pragma unroll
        for (int kk = 0; kk < SEPB / 256; ++kk) {
            int e = base + kk * 256 + tid;
            if (e < N_EDGES) {
                int s = ei[e], d = ei[N_EDGES + e];
                myPack[kk] = (s << 16) | d;
                myRank[kk] = (unsigned short)atomicAdd(&hist[d >> 7], 1);
            }
        }
        __syncthreads();

        for (int b = tid; b < NB; b += 256)
            gbase[b] = hist[b] ? atomicAdd(&cursor[b], hist[b]) : 0;
        __syncthreads();

#pragma unroll
        for (int kk = 0; kk < SEPB / 256; ++kk) {
            int e = base + kk * 256 + tid;
            if (e < N_EDGES) {
                int p = myPack[kk];
                int b = (p & 0xffff) >> 7;
                int pos2 = gbase[b] + myRank[kk];
                if (pos2 < (b + 1) * BKT) packs[pos2] = p;  // overflow-drop guard
            }
        }
        return;
    }

    kA_body((blockIdx.x - SBLKS) * 16, tid, x, pos, WT, fb, nb1, lW1f, u, v,
            SL, pw);
}

// ---------------------------------------------------------------------------
// kSortA: blocks [0,NB): per-bucket rank scatter into fixed-stride srcList
// (cur[] LDS atomics), deg write, sentinel pad fill.
// Blocks [NB, NB + NGRP-KSPLIT): kA groups [KSPLIT, NGRP) — hide the sort's
// 391-block underfill.
// ---------------------------------------------------------------------------
__global__ __launch_bounds__(256) void kSortA(
    const int* __restrict__ cursor, const int* __restrict__ packs,
    unsigned short* __restrict__ srcList, int* __restrict__ degArr,
    const float* __restrict__ x, const float* __restrict__ pos,
    const unsigned short* __restrict__ WT, const float* __restrict__ fb,
    const float* __restrict__ nb1,
    const float* __restrict__ lW1f,
    unsigned short* __restrict__ u, unsigned short* __restrict__ v) {
    __shared__ int cur[128];
    __shared__ unsigned short SL[2][16 * XPITCH];
    __shared__ float pw[48];
    int tid = threadIdx.x;

    if (blockIdx.x < NB) {
        int nbk = blockIdx.x;
        int nodeBase = nbk * 128;
        int nvalid = min(128, N_NODES - nodeBase);
        int eb = nbk * BKT;
        int ee = min(cursor[nbk], (nbk + 1) * BKT);

        if (tid < 128) cur[tid] = 0;
        __syncthreads();
        for (int i = eb + tid; i < ee; i += 256) {
            int p = packs[i];
            int node = p & 127;
            int r = atomicAdd(&cur[node], 1);
            if (r < STRIDE)
                srcList[(size_t)(nodeBase + node) * STRIDE + r] =
                    (unsigned short)(((unsigned)p) >> 16);
        }
        __syncthreads();
        if (tid < nvalid) {
            int d = min(cur[tid], STRIDE);
            degArr[nodeBase + tid] = d;
            int pd = (d + 15) & ~15;
            size_t b2 = (size_t)(nodeBase + tid) * STRIDE;
            for (int r = d; r < pd; ++r) srcList[b2 + r] = (unsigned short)SENT;
        }
        return;
    }

    kA_body((KSPLIT + blockIdx.x - NB) * 16, tid, x, pos, WT, fb, nb1, lW1f,
            u, v, SL, pw);
}

// ---------------------------------------------------------------------------
// kB (layers 0,1): fused agg + FOLDED chain with double-buffered SL (each
// stage reads buf p, writes p^1 -> 1 barrier/stage).
// [G_l=lW2·gW1](relu) -> gW2(relu) -> aT(l+1)/bT(l+1). u in-place; v ping-pong.
// ---------------------------------------------------------------------------
__global__ __launch_bounds__(256) void kB(
    const float* __restrict__ pos, const int* __restrict__ degArr,
    const unsigned short* __restrict__ srcList,
    const unsigned short* __restrict__ WT, const float* __restrict__ fb, int l,
    const float* __restrict__ gb1, const float* __restrict__ gb2,
    const float* __restrict__ lW1f_next, const float* __restrict__ b1n,
    unsigned short* __restrict__ u,
    const unsigned short* __restrict__ vin,
    unsigned short* __restrict__ vout) {
    __shared__ unsigned short SL[2][16 * XPITCH];
    __shared__ float pw[48];
    __shared__ int dgW[16];
    int tid = threadIdx.x;
    int lane = tid & 63;
    int wv = __builtin_amdgcn_readfirstlane(tid >> 6);
    int gn0 = blockIdx.x * 16;   // N_NODES % 16 == 0
    int col = lane & 15, quad = lane >> 4;

    const unsigned short* LYR = WT + OFF_LYR + (size_t)l * LYR_SZ;
    const unsigned short* GT   = LYR + 2 * 4096;   // folded lW2·gW1
    const unsigned short* gW2T = LYR + 4 * 4096;
    const unsigned short* aTn = WT + OFF_LYR + (size_t)(l + 1) * LYR_SZ;
    const unsigned short* bTn = aTn + 4096;
    const float* lbg = fb + 128 + l * 64;

    if (tid < 48) {
        int node = gn0 + tid / 3;
        pw[tid] = pos[(size_t)node * 3 + tid % 3];
    }
    if (tid < 16) dgW[tid] = degArr[gn0 + tid];
    __syncthreads();

    wave_agg4(dgW, SL[0], u, vin, srcList, gn0, wv, lane);
    __syncthreads();

    bf16x8 a[2];
    f32x4 acc;
    float dgr[4];
#pragma unroll
    for (int r = 0; r < 4; ++r) dgr[r] = (float)dgW[quad * 4 + r];

    int ch = wv * 16 + col;
    {
        float bb = lbg[ch];      // lb2@gW1
        float g1 = gb1[ch];
        f32x4 init = {dgr[0] * bb + g1, dgr[1] * bb + g1,
                      dgr[2] * bb + g1, dgr[3] * bb + g1};
        a_load<2>(SL[0], col, quad, a);
        acc = w_tile<2, 64>(a, GT, wv, col, quad, init);
    }
    w_store1(SL[1], wv, col, quad, acc, true);   // relu (was gW1 stage's relu)
    __syncthreads();

    a_load<2>(SL[1], col, quad, a);
    acc = w_tile<2, 64>(a, gW2T, wv, col, quad, mk4(gb2[ch]));
    w_store1(SL[0], wv, col, quad, acc, true);
    __syncthreads();

    a_load<2>(SL[0], col, quad, a);
    acc = w_tile<2, 64>(a, aTn, wv, col, quad, mk4(0.f));
    g_store1(u, gn0, wv, col, quad, acc);

    const float* W1c = lW1f_next + 128 * 64;
    acc = w_tile<2, 64>(a, bTn, wv, col, quad, mk4(b1n[ch]));
    float w0 = W1c[ch], w1 = W1c[64 + ch], w2 = W1c[128 + ch];
#pragma unroll
    for (int r = 0; r < 4; ++r) {
        int rr = quad * 4 + r;
        acc[r] += pw[rr * 3 + 0] * w0 + pw[rr * 3 + 1] * w1 + pw[rr * 3 + 2] * w2;
    }
    g_store1(vout, gn0, wv, col, quad, acc);
}

// ---------------------------------------------------------------------------
// kC (layer 2): fused agg + folded chain (double-buffered SL) + readout bins.
// ---------------------------------------------------------------------------
__global__ __launch_bounds__(256) void kC(
    const int* __restrict__ degArr, const unsigned short* __restrict__ srcList,
    const int* __restrict__ batch, const unsigned short* __restrict__ WT,
    const float* __restrict__ fb,
    const float* __restrict__ gb1, const float* __restrict__ gb2,
    const float* __restrict__ lin1b, const float* __restrict__ lin2b,
    const unsigned short* __restrict__ u, const unsigned short* __restrict__ vin,
    float* __restrict__ out) {
    __shared__ unsigned short SL[2][16 * XPITCH];
    __shared__ int dgW[16];
    __shared__ int batchW[16];
    __shared__ float bins[16 * 8];
    int tid = threadIdx.x;
    int lane = tid & 63;
    int wv = __builtin_amdgcn_readfirstlane(tid >> 6);
    int gn0 = blockIdx.x * 16;   // N_NODES % 16 == 0
    int col = lane & 15, quad = lane >> 4;

    const unsigned short* LYR = WT + OFF_LYR + 2 * LYR_SZ;
    const unsigned short* GT   = LYR + 2 * 4096;   // folded lW2·gW1 (layer 2)
    const unsigned short* gW2T = LYR + 4 * 4096;
    const unsigned short* lin1T = WT + OFF_LIN1T;
    const unsigned short* lin2T = WT + OFF_LIN2T;
    const float* lbg = fb + 128 + 2 * 64;

    if (tid < 16) dgW[tid] = degArr[gn0 + tid];
    if (tid >= 32 && tid < 48) batchW[tid - 32] = batch[gn0 + tid - 32];
    if (tid >= 128 && tid < 256) bins[tid - 128] = 0.f;
    __syncthreads();

    wave_agg4(dgW, SL[0], u, vin, srcList, gn0, wv, lane);
    __syncthreads();

    bf16x8 a[2];
    f32x4 acc;
    float dgr[4];
#pragma unroll
    for (int r = 0; r < 4; ++r) dgr[r] = (float)dgW[quad * 4 + r];

    int ch = wv * 16 + col;
    {
        float bb = lbg[ch];
        float g1 = gb1[ch];
        f32x4 init = {dgr[0] * bb + g1, dgr[1] * bb + g1,
                      dgr[2] * bb + g1, dgr[3] * bb + g1};
        a_load<2>(SL[0], col, quad, a);
        acc = w_tile<2, 64>(a, GT, wv, col, quad, init);
    }
    w_store1(SL[1], wv, col, quad, acc, true);
    __syncthreads();

    a_load<2>(SL[1], col, quad, a);
    acc = w_tile<2, 64>(a, gW2T, wv, col, quad, mk4(gb2[ch]));
    w_store1(SL[0], wv, col, quad, acc, true);
    __syncthreads();

    // lin1: 32 output cols -> waves 0,1 only
    a_load<2>(SL[0], col, quad, a);
    if (wv < 2) {
        acc = w_tile<2, 64>(a, lin1T, wv, col, quad, mk4(lin1b[wv * 16 + col]));
        w_store1(SL[1], wv, col, quad, acc, true);
    }
    __syncthreads();

    // lin2: 8 output cols -> wave 0 only; accumulate into per-block bins
    if (wv == 0) {
        a_load<1>(SL[1], col, quad, a);
        f32x4 o = w_tile<1, 32>(a, lin2T, 0, col, quad,
                                mk4(col < 8 ? lin2b[col] : 0.f));
        int gmin = batchW[0];
        if (col < 8) {
#pragma unroll
            for (int r = 0; r < 4; ++r) {
                int nl = quad * 4 + r;
                atomicAdd(&bins[(batchW[nl] - gmin) * 8 + col], o[r]);
            }
        }
    }
    __syncthreads();
    int gmin = batchW[0];
    int nb8 = (batchW[15] - gmin + 1) * 8;
    for (int idx = tid; idx < nb8; idx += 256)
        atomAddF(&out[gmin * 8 + idx], bins[idx]);
}

// ---------------------------------------------------------------------------
// launch
// ---------------------------------------------------------------------------
extern "C" void kernel_launch(void* const* d_in, const int* in_sizes, int n_in,
                              void* d_out, int out_size, void* d_ws, size_t ws_size,
                              hipStream_t stream) {
    const float* x     = (const float*)d_in[0];
    const float* pos   = (const float*)d_in[1];
    const int*   ei    = (const int*)d_in[2];
    const int*   batch = (const int*)d_in[3];
    const float* nW1   = (const float*)d_in[4];
    const float* nb1   = (const float*)d_in[5];
    const float* nW2   = (const float*)d_in[6];
    const float* nb2   = (const float*)d_in[7];
    const float* lW1   = (const float*)d_in[8];
    const float* lb1   = (const float*)d_in[9];
    const float* lW2   = (const float*)d_in[10];
    const float* lb2   = (const float*)d_in[11];
    const float* gW1   = (const float*)d_in[12];
    const float* gb1   = (const float*)d_in[13];
    const float* gW2   = (const float*)d_in[14];
    const float* gb2   = (const float*)d_in[15];
    const float* lin1W = (const float*)d_in[16];
    const float* lin1b = (const float*)d_in[17];
    const float* lin2W = (const float*)d_in[18];
    const float* lin2b = (const float*)d_in[19];
    float* out = (float*)d_out;

    // workspace: u N rows; v0/v1 N+1 rows (row N = -inf sentinel)
    unsigned short* u  = (unsigned short*)d_ws;              // N*64 bf16
    unsigned short* v0 = u + (size_t)N_NODES * 64;           // (N+1)*64 bf16
    unsigned short* v1 = v0 + (size_t)(N_NODES + 1) * 64;    // (N+1)*64 bf16
    unsigned short* WT = v1 + (size_t)(N_NODES + 1) * 64;    // WT_TOTAL bf16
    int* cursor = (int*)(WT + WT_TOTAL);                     // NB
    int* degArr = cursor + NB;                               // N
    float* fbias = (float*)(degArr + N_NODES);               // 320 f32 (bA,bB,lbg)
    int* packs = (int*)(fbias + 320);                        // NB*BKT int
    unsigned short* srcList = (unsigned short*)(packs + (size_t)NB * BKT); // N*STRIDE

    kPrep<<<PBLK + 5, 256, 0, stream>>>(nW1, nW2, lW1, lW2, gW1, gW2,
                                        lin1W, lin2W, nb2, lb1, lb2,
                                        WT, fbias, cursor, out, v0, v1);
    kScatA<<<SBLKS + KSPLIT, 256, 0, stream>>>(ei, cursor, packs,
                                               x, pos, WT, fbias, nb1, lW1,
                                               u, v0);
    kSortA<<<NB + (NGRP - KSPLIT), 256, 0, stream>>>(cursor, packs, srcList,
                                                     degArr, x, pos, WT, fbias,
                                                     nb1, lW1, u, v0);

    kB<<<NGRP, 256, 0, stream>>>(
        pos, degArr, srcList, WT, fbias, 0,
        gb1 + 0, gb2 + 0,
        lW1 + (size_t)1 * 131 * 64, lb1 + 64,
        u, v0, v1);
    kB<<<NGRP, 256, 0, stream>>>(
        pos, degArr, srcList, WT, fbias, 1,
        gb1 + 64, gb2 + 64,
        lW1 + (size_t)2 * 131 * 64, lb1 + 128,
        u, v1, v0);
    kC<<<NGRP, 256, 0, stream>>>(
        degArr, srcList, batch, WT, fbias,
        gb1 + 128, gb2 + 128, lin1b, lin2b,
        u, v0, out);
}

// Round 15
// 234.269 us; speedup vs baseline: 1.0184x; 1.0184x over previous
//
#include <hip/hip_runtime.h>

#define N_NODES 50000
#define N_EDGES 800000
#define NGRAPH  128
#define XPITCH  72   // ushort pitch: 72*2=144B, 16B-aligned rows, 2-way (free) banks
#define NB      391  // dst buckets of 128 nodes
#define SEPB    8192
#define SBLKS   ((N_EDGES + SEPB - 1) / SEPB)
#define NGRP    3125 // 16-node groups (50000/16 exact)
#define STRIDE  64   // per-node srcList slots (max Poisson(16) deg << 64)
#define SENT    N_NODES  // sentinel src -> v row N_NODES = -inf => relu contribution 0
#define BKT     2560 // fixed packs region per bucket (mean 2048, +11 sigma)
#define PBLK    ((WT_TOTAL + 255) / 256)  // kPrep elementwise blocks; +5 fold appended

typedef short bf16x8 __attribute__((ext_vector_type(8)));
typedef float f32x4  __attribute__((ext_vector_type(4)));

// ---------------------------------------------------------------------------
// helpers
// ---------------------------------------------------------------------------

__device__ __forceinline__ float atomAddF(float* p, float v) {
#if defined(__gfx950__) || defined(__AMDGCN__)
    return unsafeAtomicAdd(p, v);
#else
    return atomicAdd(p, v);
#endif
}

__device__ __forceinline__ unsigned short f2bf(float x) {  // RNE f32 -> bf16
    unsigned u = __builtin_bit_cast(unsigned, x);
    u += 0x7fffu + ((u >> 16) & 1u);
    return (unsigned short)(u >> 16);
}
__device__ __forceinline__ float bf2f(unsigned short h) {
    return __builtin_bit_cast(float, (unsigned)h << 16);
}

__device__ __forceinline__ f32x4 mk4(float b) { f32x4 a = {b, b, b, b}; return a; }

// One 16x16 tile vs weight mat, A-frags preloaded in regs.
template<int NKC, int KROW>
__device__ __forceinline__ f32x4 w_tile(const bf16x8* a,
                                        const unsigned short* __restrict__ Wm,
                                        int nt, int col, int quad, f32x4 acc) {
    const unsigned short* wp = Wm + (nt * 16 + col) * KROW + quad * 8;
#pragma unroll
    for (int c = 0; c < NKC; ++c) {
        bf16x8 b = *(const bf16x8*)(wp + c * 32);
        acc = __builtin_amdgcn_mfma_f32_16x16x32_bf16(a[c], b, acc, 0, 0, 0);
    }
    return acc;
}

// load A-frags from a 16-node slice
template<int NKC>
__device__ __forceinline__ void a_load(const unsigned short* __restrict__ sl,
                                       int col, int quad, bf16x8* a) {
    a[0] = *(const bf16x8*)(sl + col * XPITCH + quad * 8);
    if (NKC > 1) a[1] = *(const bf16x8*)(sl + col * XPITCH + quad * 8 + 32);
}

// write this wave's 16-col tile into the given slice (double-buffer target)
__device__ __forceinline__ void w_store1(unsigned short* __restrict__ sl,
                                         int wv, int col, int quad, f32x4 acc,
                                         bool relu) {
#pragma unroll
    for (int r = 0; r < 4; ++r) {
        float x = acc[r];
        if (relu) x = fmaxf(x, 0.f);
        sl[(quad * 4 + r) * XPITCH + wv * 16 + col] = f2bf(x);
    }
}

// store this wave's 16-col tile to global rows (node-major bf16[64])
__device__ __forceinline__ void g_store1(unsigned short* __restrict__ g, int gn0,
                                         int wv, int col, int quad, f32x4 acc) {
#pragma unroll
    for (int r = 0; r < 4; ++r) {
        int node = gn0 + quad * 4 + r;
        if (node < N_NODES)
            g[(size_t)node * 64 + wv * 16 + col] = f2bf(acc[r]);
    }
}

// ---------------------------------------------------------------------------
// per-wave fused aggregation over sentinel-padded fixed-stride CSR.
// (Round-6 proven form: serial over the 4 nodes, 4 gathers in flight.)
// ---------------------------------------------------------------------------
__device__ __forceinline__ void wave_agg4(const int* dg, unsigned short* __restrict__ sl,
                                          const unsigned short* __restrict__ u,
                                          const unsigned short* __restrict__ vin,
                                          const unsigned short* __restrict__ srcList,
                                          int gn0, int wv, int lane) {
    int sub = lane & 15, q = lane >> 4;
    int n0 = gn0 + wv * 4;
    ushort4 uu4[4];
#pragma unroll
    for (int mi = 0; mi < 4; ++mi)
        uu4[mi] = *(const ushort4*)(u + (size_t)(n0 + mi) * 64 + sub * 4);

#pragma unroll
    for (int mi = 0; mi < 4; ++mi) {
        int m = wv * 4 + mi;
        float u0 = bf2f(uu4[mi].x), u1 = bf2f(uu4[mi].y);
        float u2 = bf2f(uu4[mi].z), u3 = bf2f(uu4[mi].w);
        int pdeg = (dg[m] + 15) & ~15;
        size_t b = (size_t)(n0 + mi) * STRIDE;
        float a0 = 0.f, a1 = 0.f, a2 = 0.f, a3 = 0.f;

        for (int g0 = 0; g0 < pdeg; g0 += 16) {
            ushort4 ss = *(const ushort4*)(srcList + b + g0 + 4 * q);  // 8B aligned
            int s0 = ss.x, s1 = ss.y, s2 = ss.z, s3 = ss.w;
            ushort4 w0 = *(const ushort4*)(vin + (size_t)s0 * 64 + sub * 4);
            ushort4 w1 = *(const ushort4*)(vin + (size_t)s1 * 64 + sub * 4);
            ushort4 w2 = *(const ushort4*)(vin + (size_t)s2 * 64 + sub * 4);
            ushort4 w3 = *(const ushort4*)(vin + (size_t)s3 * 64 + sub * 4);
            a0 += fmaxf(u0 + bf2f(w0.x), 0.f) + fmaxf(u0 + bf2f(w1.x), 0.f)
                + fmaxf(u0 + bf2f(w2.x), 0.f) + fmaxf(u0 + bf2f(w3.x), 0.f);
            a1 += fmaxf(u1 + bf2f(w0.y), 0.f) + fmaxf(u1 + bf2f(w1.y), 0.f)
                + fmaxf(u1 + bf2f(w2.y), 0.f) + fmaxf(u1 + bf2f(w3.y), 0.f);
            a2 += fmaxf(u2 + bf2f(w0.z), 0.f) + fmaxf(u2 + bf2f(w1.z), 0.f)
                + fmaxf(u2 + bf2f(w2.z), 0.f) + fmaxf(u2 + bf2f(w3.z), 0.f);
            a3 += fmaxf(u3 + bf2f(w0.w), 0.f) + fmaxf(u3 + bf2f(w1.w), 0.f)
                + fmaxf(u3 + bf2f(w2.w), 0.f) + fmaxf(u3 + bf2f(w3.w), 0.f);
        }

        a0 += __shfl_xor(a0, 16); a0 += __shfl_xor(a0, 32);
        a1 += __shfl_xor(a1, 16); a1 += __shfl_xor(a1, 32);
        a2 += __shfl_xor(a2, 16); a2 += __shfl_xor(a2, 32);
        a3 += __shfl_xor(a3, 16); a3 += __shfl_xor(a3, 32);

        if (q == 0) {
            ushort4 o;
            o.x = f2bf(a0); o.y = f2bf(a1); o.z = f2bf(a2); o.w = f2bf(a3);
            *(ushort4*)&sl[m * XPITCH + sub * 4] = o;
        }
    }
}

// ---------------------------------------------------------------------------
// kPrep: blocks [0,PBLK): elementwise transpose+bf16 (skips fold-owned/dead
// slots); zeroes out; inits cursor[b]=b*BKT (fixed bucket regions — no hist,
// no scan, no kHist dispatch); writes -inf sentinel rows.
// Blocks [PBLK,PBLK+5): f32 weight folding (R10 fast form):
//   f0: FA = nW2·A0 -> layer0 aT ; bA = nb2@A0
//   f1: FB = nW2·B0 -> layer0 bT ; bB = nb2@B0 + lb1[0]
//   f2-4: G_l = lW2_l·gW1_l -> lW2T slot l ; lbg[l] = lb2_l@gW1_l
// ---------------------------------------------------------------------------
#define OFF_NW1T  0
#define OFF_NW2T  2048
#define OFF_LYR   6144
#define LYR_SZ    20480
#define OFF_LIN1T 67584
#define OFF_LIN2T 69632
#define WT_TOTAL  70144

__global__ __launch_bounds__(256) void kPrep(
    const float* __restrict__ nW1, const float* __restrict__ nW2,
    const float* __restrict__ lW1, const float* __restrict__ lW2,
    const float* __restrict__ gW1, const float* __restrict__ gW2,
    const float* __restrict__ lin1W, const float* __restrict__ lin2W,
    const float* __restrict__ nb2, const float* __restrict__ lb1,
    const float* __restrict__ lb2,
    unsigned short* __restrict__ WT, float* __restrict__ fb,
    int* __restrict__ cursor, float* __restrict__ out,
    unsigned short* __restrict__ v0, unsigned short* __restrict__ v1) {
    int tid = threadIdx.x;

    if (blockIdx.x >= PBLK) {
        // ---- fold blocks (R10 fast form) ----
        __shared__ float foldP[64 * 65];
        int f = blockIdx.x - PBLK;
        const float* Wl;
        const float* Wr;
        size_t slot;
        if (f == 0)      { Wl = nW2;          Wr = lW1;            slot = OFF_LYR; }
        else if (f == 1) { Wl = nW2;          Wr = lW1 + 64 * 64;  slot = OFF_LYR + 4096; }
        else { int l = f - 2;
               Wl = lW2 + (size_t)l * 4096;   Wr = gW1 + (size_t)l * 4096;
               slot = OFF_LYR + (size_t)l * LYR_SZ + 2 * 4096; }

        int n = tid & 63;   // lane -> output col (coalesced Wr reads)
        int w = tid >> 6;   // wave -> 16 consecutive kk rows
        float acc[16];
#pragma unroll
        for (int i2 = 0; i2 < 16; ++i2) acc[i2] = 0.f;
        for (int t0 = 0; t0 < 64; t0 += 16) {
            float wr[16];
#pragma unroll
            for (int tt = 0; tt < 16; ++tt) wr[tt] = Wr[(t0 + tt) * 64 + n];
#pragma unroll
            for (int i2 = 0; i2 < 16; ++i2) {
                int kk = w * 16 + i2;
#pragma unroll
                for (int tt = 0; tt < 16; ++tt)
                    acc[i2] += Wl[kk * 64 + t0 + tt] * wr[tt];  // Wl wave-uniform
            }
        }
#pragma unroll
        for (int i2 = 0; i2 < 16; ++i2)
            foldP[(w * 16 + i2) * 65 + n] = acc[i2];
        __syncthreads();
        for (int idx = tid; idx < 4096; idx += 256) {
            int nn = idx >> 6, kk = idx & 63;
            WT[slot + idx] = f2bf(foldP[kk * 65 + nn]);   // coalesced WT write
        }
        if (tid < 64) {
            if (f == 0) {
                float s = 0.f;
                for (int t = 0; t < 64; ++t) s += nb2[t] * lW1[t * 64 + tid];
                fb[tid] = s;                     // bA
            } else if (f == 1) {
                float s = 0.f;
                for (int t = 0; t < 64; ++t) s += nb2[t] * lW1[(64 + t) * 64 + tid];
                fb[64 + tid] = s + lb1[tid];     // bB (+lb1 layer0)
            } else {
                int l = f - 2;
                float s = 0.f;
                for (int t = 0; t < 64; ++t)
                    s += lb2[l * 64 + t] * gW1[(size_t)l * 4096 + t * 64 + tid];
                fb[128 + l * 64 + tid] = s;      // lbg[l]
            }
        }
        return;
    }

    int i = blockIdx.x * 256 + tid;
    if (blockIdx.x == 0) {
        for (int k = tid; k < NB; k += 256) cursor[k] = k * BKT;
        for (int k = tid; k < NGRAPH * 8; k += 256) out[k] = 0.f;
    }
    if (i < 64) {  // sentinel row = -inf (bf16 0xFF80)
        v0[(size_t)N_NODES * 64 + i] = 0xFF80;
        v1[(size_t)N_NODES * 64 + i] = 0xFF80;
    }
    if (i >= WT_TOTAL) return;
    int j = i;
    if (j < 2048) {
        int n = j >> 5, k = j & 31;
        WT[i] = (k < 16) ? f2bf(nW1[k * 64 + n]) : 0;
        return;
    }
    j -= 2048;
    if (j < 4096) return;  // nW2T: dead (folded)
    j -= 4096;
    if (j < 3 * LYR_SZ) {
        int l = j / LYR_SZ;  j -= l * LYR_SZ;
        int m = j >> 12;     j &= 4095;
        if (m == 2 || m == 3 || (l == 0 && m < 2)) return;  // fold-owned / dead
        int n = j >> 6, k = j & 63;
        const float* src;
        if (m == 0)      src = lW1 + (size_t)l * 131 * 64;
        else if (m == 1) src = lW1 + (size_t)l * 131 * 64 + 64 * 64;
        else             src = gW2 + (size_t)l * 4096;
        WT[i] = f2bf(src[k * 64 + n]);
        return;
    }
    j -= 3 * LYR_SZ;
    if (j < 2048) {
        int n = j >> 6, k = j & 63;
        WT[i] = f2bf(lin1W[k * 32 + n]);
        return;
    }
    j -= 2048;
    {
        int n = j >> 5, k = j & 31;
        WT[i] = (n < 8) ? f2bf(lin2W[k * 8 + n]) : 0;
    }
}

// ---------------------------------------------------------------------------
// kScatA: merged dispatch.
// Blocks [0,SBLKS): DIRECT bucket scatter into fixed bucket regions —
// per-(block,bucket) rank via LDS hist atomics, one cursor atomic per
// touched bucket, then direct packs[gbase+rank] writes (overflow-dropped
// past the region end; BKT = mean+11sigma so statistically never).
// Blocks [SBLKS, SBLKS+NGRP): kA node pipelines (folded chain, dbuf SL) —
// independent of the scatter, hides its 98-block underfill.
// ---------------------------------------------------------------------------
__global__ __launch_bounds__(256) void kScatA(
    const int* __restrict__ ei, int* __restrict__ cursor,
    int* __restrict__ packs,
    const float* __restrict__ x, const float* __restrict__ pos,
    const unsigned short* __restrict__ WT, const float* __restrict__ fb,
    const float* __restrict__ nb1,
    const float* __restrict__ lW1f,
    unsigned short* __restrict__ u, unsigned short* __restrict__ v) {
    __shared__ int hist[NB];
    __shared__ int gbase[NB];
    __shared__ unsigned short SL[2][16 * XPITCH];
    __shared__ float pw[48];
    int tid = threadIdx.x;

    if (blockIdx.x < SBLKS) {
        int base = blockIdx.x * SEPB;
        for (int i = tid; i < NB; i += 256) hist[i] = 0;
        __syncthreads();

        int myPack[SEPB / 256];
        unsigned short myRank[SEPB / 256];
#pragma unroll
        for (int kk = 0; kk < SEPB / 256; ++kk) {
            int e = base + kk * 256 + tid;
            if (e < N_EDGES) {
                int s = ei[e], d = ei[N_EDGES + e];
                myPack[kk] = (s << 16) | d;
                myRank[kk] = (unsigned short)atomicAdd(&hist[d >> 7], 1);
            }
        }
        __syncthreads();

        for (int b = tid; b < NB; b += 256)
            gbase[b] = hist[b] ? atomicAdd(&cursor[b], hist[b]) : 0;
        __syncthreads();

#pragma unroll
        for (int kk = 0; kk < SEPB / 256; ++kk) {
            int e = base + kk * 256 + tid;
            if (e < N_EDGES) {
                int p = myPack[kk];
                int b = (p & 0xffff) >> 7;
                int pos2 = gbase[b] + myRank[kk];
                if (pos2 < (b + 1) * BKT) packs[pos2] = p;  // overflow-drop guard
            }
        }
        return;
    }

    // ---- kA body: one 16-node group, 4 waves N-split, folded chain, dbuf ----
    int gn0 = (blockIdx.x - SBLKS) * 16;
    int lane = tid & 63;
    int wv = __builtin_amdgcn_readfirstlane(tid >> 6);
    int col = lane & 15, quad = lane >> 4;

    for (int idx = tid; idx < 512; idx += 256) {
        int m = idx >> 5, k = idx & 31;
        int node = gn0 + m;
        float val = (k < 16) ? x[(size_t)node * 16 + k] : 0.f;
        SL[0][m * XPITCH + k] = f2bf(val);
    }
    if (tid < 48) {
        int node = gn0 + tid / 3;
        pw[tid] = pos[(size_t)node * 3 + tid % 3];
    }
    __syncthreads();

    bf16x8 a[2];
    f32x4 acc;

    a_load<1>(SL[0], col, quad, a);
    acc = w_tile<1, 32>(a, WT + OFF_NW1T, wv, col, quad, mk4(nb1[wv * 16 + col]));
    w_store1(SL[1], wv, col, quad, acc, true);
    __syncthreads();

    const unsigned short* FA = WT + OFF_LYR;           // nW2·A0 (folded)
    const unsigned short* FB = FA + 4096;              // nW2·B0 (folded)
    const float* W1c = lW1f + 128 * 64;
    int ch = wv * 16 + col;

    a_load<2>(SL[1], col, quad, a);
    acc = w_tile<2, 64>(a, FA, wv, col, quad, mk4(fb[ch]));       // + bA
    g_store1(u, gn0, wv, col, quad, acc);

    acc = w_tile<2, 64>(a, FB, wv, col, quad, mk4(fb[64 + ch]));  // + bB (incl lb1)
    float w0 = W1c[ch], w1 = W1c[64 + ch], w2 = W1c[128 + ch];
#pragma unroll
    for (int r = 0; r < 4; ++r) {
        int rr = quad * 4 + r;
        acc[r] += pw[rr * 3 + 0] * w0 + pw[rr * 3 + 1] * w1 + pw[rr * 3 + 2] * w2;
    }
    g_store1(v, gn0, wv, col, quad, acc);
}

// ---------------------------------------------------------------------------
// kSort: per-bucket rank scatter into the fixed-stride srcList (cur[] LDS
// atomics), deg write, sentinel pad fill. eb/ee from the fixed region +
// cursor's final value (base + count).
// ---------------------------------------------------------------------------
__global__ __launch_bounds__(256) void kSort(
    const int* __restrict__ cursor, const int* __restrict__ packs,
    unsigned short* __restrict__ srcList, int* __restrict__ degArr) {
    __shared__ int cur[128];
    int tid = threadIdx.x;
    int nbk = blockIdx.x;
    int nodeBase = nbk * 128;
    int nvalid = min(128, N_NODES - nodeBase);
    int eb = nbk * BKT;
    int ee = min(cursor[nbk], (nbk + 1) * BKT);

    if (tid < 128) cur[tid] = 0;
    __syncthreads();
    for (int i = eb + tid; i < ee; i += 256) {
        int p = packs[i];
        int node = p & 127;
        int r = atomicAdd(&cur[node], 1);
        if (r < STRIDE)
            srcList[(size_t)(nodeBase + node) * STRIDE + r] =
                (unsigned short)(((unsigned)p) >> 16);
    }
    __syncthreads();
    if (tid < nvalid) {
        int d = min(cur[tid], STRIDE);
        degArr[nodeBase + tid] = d;
        int pd = (d + 15) & ~15;
        size_t b2 = (size_t)(nodeBase + tid) * STRIDE;
        for (int r = d; r < pd; ++r) srcList[b2 + r] = (unsigned short)SENT;
    }
}

// ---------------------------------------------------------------------------
// kB (layers 0,1): fused agg + FOLDED chain with double-buffered SL (each
// stage reads buf p, writes p^1 -> 1 barrier/stage).
// [G_l=lW2·gW1](relu) -> gW2(relu) -> aT(l+1)/bT(l+1). u in-place; v ping-pong.
// ---------------------------------------------------------------------------
__global__ __launch_bounds__(256) void kB(
    const float* __restrict__ pos, const int* __restrict__ degArr,
    const unsigned short* __restrict__ srcList,
    const unsigned short* __restrict__ WT, const float* __restrict__ fb, int l,
    const float* __restrict__ gb1, const float* __restrict__ gb2,
    const float* __restrict__ lW1f_next, const float* __restrict__ b1n,
    unsigned short* __restrict__ u,
    const unsigned short* __restrict__ vin,
    unsigned short* __restrict__ vout) {
    __shared__ unsigned short SL[2][16 * XPITCH];
    __shared__ float pw[48];
    __shared__ int dgW[16];
    int tid = threadIdx.x;
    int lane = tid & 63;
    int wv = __builtin_amdgcn_readfirstlane(tid >> 6);
    int gn0 = blockIdx.x * 16;   // N_NODES % 16 == 0
    int col = lane & 15, quad = lane >> 4;

    const unsigned short* LYR = WT + OFF_LYR + (size_t)l * LYR_SZ;
    const unsigned short* GT   = LYR + 2 * 4096;   // folded lW2·gW1
    const unsigned short* gW2T = LYR + 4 * 4096;
    const unsigned short* aTn = WT + OFF_LYR + (size_t)(l + 1) * LYR_SZ;
    const unsigned short* bTn = aTn + 4096;
    const float* lbg = fb + 128 + l * 64;

    if (tid < 48) {
        int node = gn0 + tid / 3;
        pw[tid] = pos[(size_t)node * 3 + tid % 3];
    }
    if (tid < 16) dgW[tid] = degArr[gn0 + tid];
    __syncthreads();

    wave_agg4(dgW, SL[0], u, vin, srcList, gn0, wv, lane);
    __syncthreads();

    bf16x8 a[2];
    f32x4 acc;
    float dgr[4];
#pragma unroll
    for (int r = 0; r < 4; ++r) dgr[r] = (float)dgW[quad * 4 + r];

    int ch = wv * 16 + col;
    {
        float bb = lbg[ch];      // lb2@gW1
        float g1 = gb1[ch];
        f32x4 init = {dgr[0] * bb + g1, dgr[1] * bb + g1,
                      dgr[2] * bb + g1, dgr[3] * bb + g1};
        a_load<2>(SL[0], col, quad, a);
        acc = w_tile<2, 64>(a, GT, wv, col, quad, init);
    }
    w_store1(SL[1], wv, col, quad, acc, true);   // relu (was gW1 stage's relu)
    __syncthreads();

    a_load<2>(SL[1], col, quad, a);
    acc = w_tile<2, 64>(a, gW2T, wv, col, quad, mk4(gb2[ch]));
    w_store1(SL[0], wv, col, quad, acc, true);
    __syncthreads();

    a_load<2>(SL[0], col, quad, a);
    acc = w_tile<2, 64>(a, aTn, wv, col, quad, mk4(0.f));
    g_store1(u, gn0, wv, col, quad, acc);

    const float* W1c = lW1f_next + 128 * 64;
    acc = w_tile<2, 64>(a, bTn, wv, col, quad, mk4(b1n[ch]));
    float w0 = W1c[ch], w1 = W1c[64 + ch], w2 = W1c[128 + ch];
#pragma unroll
    for (int r = 0; r < 4; ++r) {
        int rr = quad * 4 + r;
        acc[r] += pw[rr * 3 + 0] * w0 + pw[rr * 3 + 1] * w1 + pw[rr * 3 + 2] * w2;
    }
    g_store1(vout, gn0, wv, col, quad, acc);
}

// ---------------------------------------------------------------------------
// kC (layer 2): fused agg + folded chain (double-buffered SL) + readout bins.
// ---------------------------------------------------------------------------
__global__ __launch_bounds__(256) void kC(
    const int* __restrict__ degArr, const unsigned short* __restrict__ srcList,
    const int* __restrict__ batch, const unsigned short* __restrict__ WT,
    const float* __restrict__ fb,
    const float* __restrict__ gb1, const float* __restrict__ gb2,
    const float* __restrict__ lin1b, const float* __restrict__ lin2b,
    const unsigned short* __restrict__ u, const unsigned short* __restrict__ vin,
    float* __restrict__ out) {
    __shared__ unsigned short SL[2][16 * XPITCH];
    __shared__ int dgW[16];
    __shared__ int batchW[16];
    __shared__ float bins[16 * 8];
    int tid = threadIdx.x;
    int lane = tid & 63;
    int wv = __builtin_amdgcn_readfirstlane(tid >> 6);
    int gn0 = blockIdx.x * 16;   // N_NODES % 16 == 0
    int col = lane & 15, quad = lane >> 4;

    const unsigned short* LYR = WT + OFF_LYR + 2 * LYR_SZ;
    const unsigned short* GT   = LYR + 2 * 4096;   // folded lW2·gW1 (layer 2)
    const unsigned short* gW2T = LYR + 4 * 4096;
    const unsigned short* lin1T = WT + OFF_LIN1T;
    const unsigned short* lin2T = WT + OFF_LIN2T;
    const float* lbg = fb + 128 + 2 * 64;

    if (tid < 16) dgW[tid] = degArr[gn0 + tid];
    if (tid >= 32 && tid < 48) batchW[tid - 32] = batch[gn0 + tid - 32];
    if (tid >= 128 && tid < 256) bins[tid - 128] = 0.f;
    __syncthreads();

    wave_agg4(dgW, SL[0], u, vin, srcList, gn0, wv, lane);
    __syncthreads();

    bf16x8 a[2];
    f32x4 acc;
    float dgr[4];
#pragma unroll
    for (int r = 0; r < 4; ++r) dgr[r] = (float)dgW[quad * 4 + r];

    int ch = wv * 16 + col;
    {
        float bb = lbg[ch];
        float g1 = gb1[ch];
        f32x4 init = {dgr[0] * bb + g1, dgr[1] * bb + g1,
                      dgr[2] * bb + g1, dgr[3] * bb + g1};
        a_load<2>(SL[0], col, quad, a);
        acc = w_tile<2, 64>(a, GT, wv, col, quad, init);
    }
    w_store1(SL[1], wv, col, quad, acc, true);
    __syncthreads();

    a_load<2>(SL[1], col, quad, a);
    acc = w_tile<2, 64>(a, gW2T, wv, col, quad, mk4(gb2[ch]));
    w_store1(SL[0], wv, col, quad, acc, true);
    __syncthreads();

    // lin1: 32 output cols -> waves 0,1 only
    a_load<2>(SL[0], col, quad, a);
    if (wv < 2) {
        acc = w_tile<2, 64>(a, lin1T, wv, col, quad, mk4(lin1b[wv * 16 + col]));
        w_store1(SL[1], wv, col, quad, acc, true);
    }
    __syncthreads();

    // lin2: 8 output cols -> wave 0 only; accumulate into per-block bins
    if (wv == 0) {
        a_load<1>(SL[1], col, quad, a);
        f32x4 o = w_tile<1, 32>(a, lin2T, 0, col, quad,
                                mk4(col < 8 ? lin2b[col] : 0.f));
        int gmin = batchW[0];
        if (col < 8) {
#pragma unroll
            for (int r = 0; r < 4; ++r) {
                int nl = quad * 4 + r;
                atomicAdd(&bins[(batchW[nl] - gmin) * 8 + col], o[r]);
            }
        }
    }
    __syncthreads();
    int gmin = batchW[0];
    int nb8 = (batchW[15] - gmin + 1) * 8;
    for (int idx = tid; idx < nb8; idx += 256)
        atomAddF(&out[gmin * 8 + idx], bins[idx]);
}

// ---------------------------------------------------------------------------
// launch
// ---------------------------------------------------------------------------
extern "C" void kernel_launch(void* const* d_in, const int* in_sizes, int n_in,
                              void* d_out, int out_size, void* d_ws, size_t ws_size,
                              hipStream_t stream) {
    const float* x     = (const float*)d_in[0];
    const float* pos   = (const float*)d_in[1];
    const int*   ei    = (const int*)d_in[2];
    const int*   batch = (const int*)d_in[3];
    const float* nW1   = (const float*)d_in[4];
    const float* nb1   = (const float*)d_in[5];
    const float* nW2   = (const float*)d_in[6];
    const float* nb2   = (const float*)d_in[7];
    const float* lW1   = (const float*)d_in[8];
    const float* lb1   = (const float*)d_in[9];
    const float* lW2   = (const float*)d_in[10];
    const float* lb2   = (const float*)d_in[11];
    const float* gW1   = (const float*)d_in[12];
    const float* gb1   = (const float*)d_in[13];
    const float* gW2   = (const float*)d_in[14];
    const float* gb2   = (const float*)d_in[15];
    const float* lin1W = (const float*)d_in[16];
    const float* lin1b = (const float*)d_in[17];
    const float* lin2W = (const float*)d_in[18];
    const float* lin2b = (const float*)d_in[19];
    float* out = (float*)d_out;

    // workspace: u N rows; v0/v1 N+1 rows (row N = -inf sentinel)
    unsigned short* u  = (unsigned short*)d_ws;              // N*64 bf16
    unsigned short* v0 = u + (size_t)N_NODES * 64;           // (N+1)*64 bf16
    unsigned short* v1 = v0 + (size_t)(N_NODES + 1) * 64;    // (N+1)*64 bf16
    unsigned short* WT = v1 + (size_t)(N_NODES + 1) * 64;    // WT_TOTAL bf16
    int* cursor = (int*)(WT + WT_TOTAL);                     // NB
    int* degArr = cursor + NB;                               // N
    float* fbias = (float*)(degArr + N_NODES);               // 320 f32 (bA,bB,lbg)
    int* packs = (int*)(fbias + 320);                        // NB*BKT int
    unsigned short* srcList = (unsigned short*)(packs + (size_t)NB * BKT); // N*STRIDE

    kPrep<<<PBLK + 5, 256, 0, stream>>>(nW1, nW2, lW1, lW2, gW1, gW2,
                                        lin1W, lin2W, nb2, lb1, lb2,
                                        WT, fbias, cursor, out, v0, v1);
    kScatA<<<SBLKS + NGRP, 256, 0, stream>>>(ei, cursor, packs,
                                             x, pos, WT, fbias, nb1, lW1, u, v0);
    kSort<<<NB, 256, 0, stream>>>(cursor, packs, srcList, degArr);

    kB<<<NGRP, 256, 0, stream>>>(
        pos, degArr, srcList, WT, fbias, 0,
        gb1 + 0, gb2 + 0,
        lW1 + (size_t)1 * 131 * 64, lb1 + 64,
        u, v0, v1);
    kB<<<NGRP, 256, 0, stream>>>(
        pos, degArr, srcList, WT, fbias, 1,
        gb1 + 64, gb2 + 64,
        lW1 + (size_t)2 * 131 * 64, lb1 + 128,
        u, v1, v0);
    kC<<<NGRP, 256, 0, stream>>>(
        degArr, srcList, batch, WT, fbias,
        gb1 + 128, gb2 + 128, lin1b, lin2b,
        u, v0, out);
}